// Round 5
// baseline (624.747 us; speedup 1.0000x reference)
//
#include <hip/hip_runtime.h>
#include <hip/hip_bf16.h>

#define BB 128
#define TT 512
#define EE 128
#define HH 256
#define MM 1024
#define CC 5

typedef _Float16 h2 __attribute__((ext_vector_type(2)));

__device__ inline h2 mkh2(float a, float b) {
    // v_cvt_pkrtz_f16_f32: 1 instr; builtin returns __fp16x2, bit-identical
    return __builtin_bit_cast(h2, __builtin_amdgcn_cvt_pkrtz(a, b));
}

__device__ inline float dot2f(h2 a, h2 b, float c) {
#if __has_builtin(__builtin_amdgcn_fdot2)
    return __builtin_amdgcn_fdot2(a, b, c, false);
#else
    return c + (float)a.x * (float)b.x + (float)a.y * (float)b.y;
#endif
}

// Quad butterfly sum via DPP (VALU pipe, no LDS traffic).
__device__ inline float dpp_add4(float x) {
    int t = __builtin_amdgcn_update_dpp(0, __builtin_bit_cast(int, x), 0xB1, 0xF, 0xF, true);
    x += __builtin_bit_cast(float, t);
    t = __builtin_amdgcn_update_dpp(0, __builtin_bit_cast(int, x), 0x4E, 0xF, 0xF, true);
    x += __builtin_bit_cast(float, t);
    return x;
}

// Workgroup barrier WITHOUT the vmcnt(0) drain __syncthreads() emits.
// Safe here: cross-thread data lives only in LDS (lgkmcnt(0) waited);
// outstanding global loads are private prefetches and may stay in flight.
__device__ inline void barrier_nodrain() {
    asm volatile("s_waitcnt lgkmcnt(0)\n\ts_barrier" ::: "memory");
}

__device__ inline float fast_tanh(float x) {
    float e = __expf(2.0f * x);
    return 1.0f - 2.0f / (e + 1.0f);
}

// ---------------------------------------------------------------------------
// K1: u[b][t][j] = b_ih[j]+b_hh[j] + dot(emb[x[b][t]], W_ih[j])  (f16 out)
// Barrier-free: emb row read via wave-uniform broadcast dwordx4 loads; token
// ids pre-staged in a register (lane ln holds x[base+ln]) and broadcast with
// __shfl. 4 wgs/CU x 4 waves hide the random emb-row gather latency.
// R4 bug fixed: dot loop now covers all 32 float4 (128 elements), not 16.
// ---------------------------------------------------------------------------
__global__ __launch_bounds__(256, 4)
void k_embed(const int* __restrict__ x, const int* __restrict__ lengths,
             const float* __restrict__ emb, const float* __restrict__ W_ih,
             const float* __restrict__ b_ih, const float* __restrict__ b_hh,
             _Float16* __restrict__ u)
{
    const int b = blockIdx.y;
    const int base = blockIdx.x * 64;       // 64-token chunk
    const int len = lengths[b];
    const int t0 = TT - len;
    const int ts = (base > t0) ? base : t0;
    const int te = base + 64;
    if (ts >= te) return;                   // uniform per block
    const int tid = threadIdx.x;
    const int ln = tid & 63;

    // W_ih row tid as f16 pairs: 64 VGPRs
    h2 w[64];
    const float4* wr = (const float4*)(W_ih + (size_t)tid * EE);
    #pragma unroll
    for (int q = 0; q < 32; ++q) {
        float4 v = wr[q];
        w[2*q]   = mkh2(v.x, v.y);
        w[2*q+1] = mkh2(v.z, v.w);
    }
    const float bias = b_ih[tid] + b_hh[tid];
    const int xv = x[(size_t)b * TT + base + ln];   // chunk token ids, 1 VGPR

    for (int t = ts; t < te; ++t) {
        const int tok = __shfl(xv, t - base, 64);
        const float4* er = (const float4*)(emb + (size_t)tok * EE);
        float acc = bias;
        #pragma unroll
        for (int q = 0; q < 32; ++q) {       // FULL 128-element dot
            float4 v = er[q];                // wave-uniform address: broadcast
            acc = dot2f(w[2*q],   mkh2(v.x, v.y), acc);
            acc = dot2f(w[2*q+1], mkh2(v.z, v.w), acc);
        }
        u[((size_t)b * TT + t) * HH + tid] = (_Float16)acc;   // coalesced
    }
}

// ---------------------------------------------------------------------------
// K2: serial scan, one workgroup per batch element. Split-K(4) + DPP reduce
// + two fixes for the barrier-drain stall R2's counters exposed
// (1385 cyc/step, VALUBusy 12%):
//   (a) barrier_nodrain() instead of __syncthreads() -> u prefetch loads are
//       NOT drained at each step barrier;
//   (b) u prefetch pipeline of depth 4 via manual 4x unroll (no register
//       rotation copies), so each u value has ~4 steps of latency hiding.
// ---------------------------------------------------------------------------
__global__ __launch_bounds__(256, 1)
void k_rnn(const int* __restrict__ lengths, const float* __restrict__ W_hh,
           const _Float16* __restrict__ u, float* __restrict__ hn)
{
    const int b = blockIdx.x;
    const int tid = threadIdx.x;
    const int kc = tid & 3;
    const int g  = tid >> 2;
    const int len = lengths[b];

    // W_hh rows 4g..4g+3, cols [kc*64, kc*64+64) as f16 pairs: 128 VGPRs
    h2 w[4][32];
    #pragma unroll
    for (int m = 0; m < 4; ++m) {
        const float4* wr = (const float4*)(W_hh + (size_t)(4*g + m) * HH + kc*64);
        #pragma unroll
        for (int q = 0; q < 16; ++q) {
            float4 v = wr[q];
            w[m][2*q]   = mkh2(v.x, v.y);
            w[m][2*q+1] = mkh2(v.z, v.w);
        }
    }

    __shared__ char hbuf[2][512];
    ((float*)hbuf)[tid] = 0.f;          // zero both buffers (256*4B)

    // swizzled write slot for logical j = tid (constant across steps)
    const int wr_off = (tid >> 6) * 128
                     + (((((tid >> 3) & 7) + 2 * (tid >> 6)) & 7) << 4)
                     + ((tid & 7) << 1);
    // swizzled read offsets: iter i reads h[kc*64 + 8i .. +7], conflict-free
    int roff[8];
    #pragma unroll
    for (int i = 0; i < 8; ++i)
        roff[i] = kc * 128 + (((i + 2 * kc) & 7) << 4);

    barrier_nodrain();                  // publish zeroed hbuf

    float hlast = 0.f;
    if (len > 0) {
        const _Float16* up = u + ((size_t)b * TT + (TT - len)) * HH + tid;
        _Float16 u0 = up[0];
        _Float16 u1 = up[(size_t)((1 < len) ? 1 : len - 1) * HH];
        _Float16 u2 = up[(size_t)((2 < len) ? 2 : len - 1) * HH];
        _Float16 u3 = up[(size_t)((3 < len) ? 3 : len - 1) * HH];
        int t = 0, p = 0;

#define RNN_STEP(UX)                                                      \
        {                                                                 \
            const char* hb = hbuf[p];                                     \
            float a0 = 0.f, a1 = 0.f, a2 = 0.f, a3 = 0.f;                 \
            _Pragma("unroll")                                             \
            for (int i = 0; i < 8; ++i) {                                 \
                float4 hv = *(const float4*)(hb + roff[i]);               \
                h2* hp = (h2*)&hv;                                        \
                _Pragma("unroll")                                         \
                for (int z = 0; z < 4; ++z) {                             \
                    a0 = dot2f(w[0][4*i+z], hp[z], a0);                   \
                    a1 = dot2f(w[1][4*i+z], hp[z], a1);                   \
                    a2 = dot2f(w[2][4*i+z], hp[z], a2);                   \
                    a3 = dot2f(w[3][4*i+z], hp[z], a3);                   \
                }                                                         \
            }                                                             \
            const int tn = (t + 4 < len) ? (t + 4) : (len - 1);           \
            _Float16 un = up[(size_t)tn * HH];  /* stays in flight */     \
            a0 = dpp_add4(a0); a1 = dpp_add4(a1);                         \
            a2 = dpp_add4(a2); a3 = dpp_add4(a3);                         \
            float v = (kc == 0) ? a0 : (kc == 1) ? a1                     \
                    : (kc == 2) ? a2 : a3;                                \
            const float hnew = fast_tanh(v + (float)(UX));                \
            hlast = hnew;                                                 \
            *(_Float16*)(hbuf[p ^ 1] + wr_off) = (_Float16)hnew;          \
            UX = un;                                                      \
            barrier_nodrain();                                            \
            p ^= 1;                                                       \
        }

        while (true) {
            RNN_STEP(u0); if (++t == len) break;
            RNN_STEP(u1); if (++t == len) break;
            RNN_STEP(u2); if (++t == len) break;
            RNN_STEP(u3); if (++t == len) break;
        }
#undef RNN_STEP
    }
    hn[(size_t)b * HH + tid] = hlast;
}

// ---------------------------------------------------------------------------
// K3: MLP head + log_softmax. One block per batch row. (unchanged)
// ---------------------------------------------------------------------------
__global__ __launch_bounds__(256, 2)
void k_head(const float* __restrict__ hn, const float* __restrict__ W0,
            const float* __restrict__ b0, const float* __restrict__ W1,
            const float* __restrict__ b1, float* __restrict__ out)
{
    const int b = blockIdx.x;
    const int tid = threadIdx.x;
    __shared__ float sh[HH];
    __shared__ float sh1[MM];
    __shared__ float sred[CC][4];
    __shared__ float slog[CC];

    sh[tid] = hn[(size_t)b * HH + tid];
    __syncthreads();

    float acc[4];
    #pragma unroll
    for (int i = 0; i < 4; ++i) acc[i] = b0[tid + 256 * i];
    const float4* sh4 = (const float4*)sh;
    for (int k4 = 0; k4 < HH / 4; ++k4) {
        float4 hv = sh4[k4];
        #pragma unroll
        for (int i = 0; i < 4; ++i) {
            float4 wv = ((const float4*)(W0 + (size_t)(tid + 256 * i) * HH))[k4];
            acc[i] += wv.x * hv.x + wv.y * hv.y + wv.z * hv.z + wv.w * hv.w;
        }
    }
    #pragma unroll
    for (int i = 0; i < 4; ++i) sh1[tid + 256 * i] = fmaxf(acc[i], 0.f);
    __syncthreads();

    float pc[CC] = {0.f, 0.f, 0.f, 0.f, 0.f};
    for (int k = tid; k < MM; k += 256) {
        float hv = sh1[k];
        #pragma unroll
        for (int c = 0; c < CC; ++c) pc[c] += W1[(size_t)c * MM + k] * hv;
    }
    const int lane = tid & 63, wid = tid >> 6;
    #pragma unroll
    for (int c = 0; c < CC; ++c) {
        float v = pc[c];
        #pragma unroll
        for (int off = 32; off > 0; off >>= 1) v += __shfl_down(v, off, 64);
        if (lane == 0) sred[c][wid] = v;
    }
    __syncthreads();
    if (tid < CC) {
        float s = sred[tid][0] + sred[tid][1] + sred[tid][2] + sred[tid][3]
                + b1[tid];
        slog[tid] = fmaxf(s, 0.f);
    }
    __syncthreads();
    if (tid < CC) {
        float mx = slog[0];
        #pragma unroll
        for (int c = 1; c < CC; ++c) mx = fmaxf(mx, slog[c]);
        float se = 0.f;
        #pragma unroll
        for (int c = 0; c < CC; ++c) se += __expf(slog[c] - mx);
        out[(size_t)b * CC + tid] = slog[tid] - mx - __logf(se);
    }
}

// ---------------------------------------------------------------------------
extern "C" void kernel_launch(void* const* d_in, const int* in_sizes, int n_in,
                              void* d_out, int out_size, void* d_ws, size_t ws_size,
                              hipStream_t stream) {
    const int*   x       = (const int*)d_in[0];
    const int*   lengths = (const int*)d_in[1];
    const float* emb     = (const float*)d_in[2];
    const float* W_ih    = (const float*)d_in[3];
    const float* W_hh    = (const float*)d_in[4];
    const float* b_ih    = (const float*)d_in[5];
    const float* b_hh    = (const float*)d_in[6];
    const float* W0      = (const float*)d_in[7];
    const float* b0      = (const float*)d_in[8];
    const float* W1      = (const float*)d_in[9];
    const float* b1      = (const float*)d_in[10];
    float* out = (float*)d_out;

    _Float16* u  = (_Float16*)d_ws;
    float*    hn = (float*)((char*)d_ws + (size_t)BB * TT * HH * sizeof(_Float16));

    dim3 g1(TT / 64, BB);
    k_embed<<<g1, 256, 0, stream>>>(x, lengths, emb, W_ih, b_ih, b_hh, u);
    k_rnn  <<<BB, 256, 0, stream>>>(lengths, W_hh, u, hn);
    k_head <<<BB, 256, 0, stream>>>(hn, W0, b0, W1, b1, out);
}

// Round 6
// 459.594 us; speedup vs baseline: 1.3593x; 1.3593x over previous
//
#include <hip/hip_runtime.h>
#include <hip/hip_bf16.h>

#define BB 128
#define TT 512
#define EE 128
#define HH 256
#define MM 1024
#define CC 5

typedef _Float16 h2 __attribute__((ext_vector_type(2)));

struct alignas(16) H8 { h2 v0, v1, v2, v3; };   // 8 f16 = one b128

__device__ inline h2 mkh2(float a, float b) {
    return __builtin_bit_cast(h2, __builtin_amdgcn_cvt_pkrtz(a, b));
}

__device__ inline float dot2f(h2 a, h2 b, float c) {
#if __has_builtin(__builtin_amdgcn_fdot2)
    return __builtin_amdgcn_fdot2(a, b, c, false);
#else
    return c + (float)a.x * (float)b.x + (float)a.y * (float)b.y;
#endif
}

// Quad butterfly sum via DPP (VALU pipe, no LDS traffic).
__device__ inline float dpp_add4(float x) {
    int t = __builtin_amdgcn_update_dpp(0, __builtin_bit_cast(int, x), 0xB1, 0xF, 0xF, true);
    x += __builtin_bit_cast(float, t);
    t = __builtin_amdgcn_update_dpp(0, __builtin_bit_cast(int, x), 0x4E, 0xF, 0xF, true);
    x += __builtin_bit_cast(float, t);
    return x;
}

__device__ inline float fast_tanh(float x) {
    float e = __expf(2.0f * x);
    return 1.0f - 2.0f / (e + 1.0f);
}

// ---------------------------------------------------------------------------
// K1: u[b][t][ch] = b_ih+b_hh + dot(emb[x[b][t]], W_ih[ch])  (f16 out)
// 16-token phases: coalesced gather of 16 emb rows -> f16 LDS (each thread
// 32B global -> 16B LDS), then split-K(4)+DPP compute from LDS broadcasts.
// 2 barriers per 16 tokens (vs 1/token in R2, vs latency-bound R5 form).
// ---------------------------------------------------------------------------
__global__ __launch_bounds__(256, 4)
void k_embed(const int* __restrict__ x, const int* __restrict__ lengths,
             const float* __restrict__ emb, const float* __restrict__ W_ih,
             const float* __restrict__ b_ih, const float* __restrict__ b_hh,
             _Float16* __restrict__ u)
{
    const int b = blockIdx.y;
    const int base = blockIdx.x * 64;       // 64-token chunk
    const int len = lengths[b];
    const int t0 = TT - len;
    const int ts = (base > t0) ? base : t0;
    const int te = base + 64;
    if (ts >= te) return;                   // uniform per block
    const int tid = threadIdx.x;
    const int kc = tid & 3;
    const int g  = tid >> 2;

    // W_ih rows 4g..4g+3, K-chunk [kc*32, kc*32+32) as f16 pairs: 64 VGPRs
    h2 w[4][16];
    #pragma unroll
    for (int m = 0; m < 4; ++m) {
        const float4* wr = (const float4*)(W_ih + (size_t)(4*g + m) * EE + kc*32);
        #pragma unroll
        for (int q = 0; q < 8; ++q) {
            float4 v = wr[q];
            w[m][2*q]   = mkh2(v.x, v.y);
            w[m][2*q+1] = mkh2(v.z, v.w);
        }
    }
    const float bias = b_ih[tid] + b_hh[tid];   // channel tid (kept lane)

    __shared__ __align__(16) char sbuf[16 * 256];  // 16 rows x 256B f16
    const int r  = tid >> 4;    // row 0..15
    const int sg = tid & 15;    // 16B segment 0..15

    const int p0 = (ts - base) >> 4;        // first phase containing ts
    for (int ph = p0; ph < 4; ++ph) {
        // gather: row r of this phase, 32B/thread, coalesced per 16 threads
        int tr = base + ph * 16 + r;
        tr = (tr < ts) ? ts : tr;           // clamp into active region
        const int tok = x[(size_t)b * TT + tr];
        const float4* ep = (const float4*)(emb + (size_t)tok * EE + sg * 8);
        float4 ra = ep[0], rb = ep[1];
        __syncthreads();                    // prev phase compute done
        {
            H8 pk;
            pk.v0 = mkh2(ra.x, ra.y); pk.v1 = mkh2(ra.z, ra.w);
            pk.v2 = mkh2(rb.x, rb.y); pk.v3 = mkh2(rb.z, rb.w);
            *(H8*)(sbuf + r * 256 + sg * 16) = pk;
        }
        __syncthreads();                    // LDS rows ready
        #pragma unroll 4
        for (int tl = 0; tl < 16; ++tl) {
            const int t = base + ph * 16 + tl;
            const char* row = sbuf + tl * 256 + kc * 64;
            float a0 = 0.f, a1 = 0.f, a2 = 0.f, a3 = 0.f;
            #pragma unroll
            for (int i = 0; i < 4; ++i) {
                float4 hv = *(const float4*)(row + i * 16);  // broadcast
                h2* hp = (h2*)&hv;
                #pragma unroll
                for (int z = 0; z < 4; ++z) {
                    a0 = dot2f(w[0][4*i+z], hp[z], a0);
                    a1 = dot2f(w[1][4*i+z], hp[z], a1);
                    a2 = dot2f(w[2][4*i+z], hp[z], a2);
                    a3 = dot2f(w[3][4*i+z], hp[z], a3);
                }
            }
            a0 = dpp_add4(a0); a1 = dpp_add4(a1);
            a2 = dpp_add4(a2); a3 = dpp_add4(a3);
            float v = (kc == 0) ? a0 : (kc == 1) ? a1 : (kc == 2) ? a2 : a3;
            if (t >= ts)                    // uniform guard
                u[((size_t)b * TT + t) * HH + tid] = (_Float16)(v + bias);
        }
    }
}

// ---------------------------------------------------------------------------
// K2: serial scan, one workgroup per batch element. Split-K(4) + DPP.
// R5 lesson: ANY per-step global load is drained by the per-step barrier
// (LLVM emits vmcnt(0) before s_barrier AND before memory-clobber asm), so
// u is staged in 64-step chunks (32 KB LDS) with coalesced dwordx4 loads —
// global latency exposed once per 64 steps. Inner loop is LDS-only; plain
// __syncthreads() is then drain-free by construction.
// ---------------------------------------------------------------------------
__global__ __launch_bounds__(256, 1)
void k_rnn(const int* __restrict__ lengths, const float* __restrict__ W_hh,
           const _Float16* __restrict__ u, float* __restrict__ hn)
{
    const int b = blockIdx.x;
    const int tid = threadIdx.x;
    const int kc = tid & 3;
    const int g  = tid >> 2;
    const int len = lengths[b];

    // W_hh rows 4g..4g+3, cols [kc*64, kc*64+64) as f16 pairs: 128 VGPRs
    h2 w[4][32];
    #pragma unroll
    for (int m = 0; m < 4; ++m) {
        const float4* wr = (const float4*)(W_hh + (size_t)(4*g + m) * HH + kc*64);
        #pragma unroll
        for (int q = 0; q < 16; ++q) {
            float4 v = wr[q];
            w[m][2*q]   = mkh2(v.x, v.y);
            w[m][2*q+1] = mkh2(v.z, v.w);
        }
    }

    __shared__ char hbuf[2][512];                 // 2 x 256 f16
    __shared__ __align__(16) char ubuf[64 * 512]; // 64 steps x 256ch x 2B
    ((float*)hbuf)[tid] = 0.f;                    // zero both h buffers

    // swizzled write slot for logical channel j = tid
    const int wr_off = (tid >> 6) * 128
                     + (((((tid >> 3) & 7) + 2 * (tid >> 6)) & 7) << 4)
                     + ((tid & 7) << 1);
    // swizzled read offsets: iter i reads h[kc*64 + 8i .. +7], conflict-free
    int roff[8];
    #pragma unroll
    for (int i = 0; i < 8; ++i)
        roff[i] = kc * 128 + (((i + 2 * kc) & 7) << 4);

    __syncthreads();                              // publish zeroed hbuf

    float hlast = 0.f;
    if (len > 0) {
        const char* ubase = (const char*)(u + ((size_t)b * TT + (TT - len)) * HH);
        const int totbytes = len * 512;           // active-region bytes
        int p = 0;
        for (int c = 0; c * 64 < len; ++c) {
            // ---- stage chunk c: 64 steps x 512B = 32 KB, coalesced ----
            const int cbase = c * 32768;
            float4 stash[8];
            #pragma unroll
            for (int q = 0; q < 8; ++q) {
                int off = cbase + q * 4096 + tid * 16;
                off = (off > totbytes - 16) ? (totbytes - 16) : off; // clamp
                stash[q] = *(const float4*)(ubase + off);
            }
            // prev chunk's reads finished at its last step barrier
            #pragma unroll
            for (int q = 0; q < 8; ++q)           // vmcnt wait lands here
                *(float4*)(ubuf + q * 4096 + tid * 16) = stash[q];
            __syncthreads();                      // nothing left in flight
            // ---- 64 LDS-only steps ----
            const int steps = (len - c * 64 < 64) ? (len - c * 64) : 64;
            for (int s = 0; s < steps; ++s) {
                const _Float16 uv = *(const _Float16*)(ubuf + s * 512 + tid * 2);
                const char* hb = hbuf[p];
                float a0 = 0.f, a1 = 0.f, a2 = 0.f, a3 = 0.f;
                #pragma unroll
                for (int i = 0; i < 8; ++i) {
                    float4 hv = *(const float4*)(hb + roff[i]); // conflict-free
                    h2* hp = (h2*)&hv;
                    #pragma unroll
                    for (int z = 0; z < 4; ++z) {
                        a0 = dot2f(w[0][4*i+z], hp[z], a0);
                        a1 = dot2f(w[1][4*i+z], hp[z], a1);
                        a2 = dot2f(w[2][4*i+z], hp[z], a2);
                        a3 = dot2f(w[3][4*i+z], hp[z], a3);
                    }
                }
                a0 = dpp_add4(a0); a1 = dpp_add4(a1);
                a2 = dpp_add4(a2); a3 = dpp_add4(a3);
                float v = (kc == 0) ? a0 : (kc == 1) ? a1
                        : (kc == 2) ? a2 : a3;
                const float hnew = fast_tanh(v + (float)uv);
                hlast = hnew;
                *(_Float16*)(hbuf[p ^ 1] + wr_off) = (_Float16)hnew;
                __syncthreads();                  // LDS-only: no vm drain
                p ^= 1;
            }
        }
    }
    hn[(size_t)b * HH + tid] = hlast;             // len==0 -> 0, matches ref
}

// ---------------------------------------------------------------------------
// K3: MLP head + log_softmax. One block per batch row. (unchanged)
// ---------------------------------------------------------------------------
__global__ __launch_bounds__(256, 2)
void k_head(const float* __restrict__ hn, const float* __restrict__ W0,
            const float* __restrict__ b0, const float* __restrict__ W1,
            const float* __restrict__ b1, float* __restrict__ out)
{
    const int b = blockIdx.x;
    const int tid = threadIdx.x;
    __shared__ float sh[HH];
    __shared__ float sh1[MM];
    __shared__ float sred[CC][4];
    __shared__ float slog[CC];

    sh[tid] = hn[(size_t)b * HH + tid];
    __syncthreads();

    float acc[4];
    #pragma unroll
    for (int i = 0; i < 4; ++i) acc[i] = b0[tid + 256 * i];
    const float4* sh4 = (const float4*)sh;
    for (int k4 = 0; k4 < HH / 4; ++k4) {
        float4 hv = sh4[k4];
        #pragma unroll
        for (int i = 0; i < 4; ++i) {
            float4 wv = ((const float4*)(W0 + (size_t)(tid + 256 * i) * HH))[k4];
            acc[i] += wv.x * hv.x + wv.y * hv.y + wv.z * hv.z + wv.w * hv.w;
        }
    }
    #pragma unroll
    for (int i = 0; i < 4; ++i) sh1[tid + 256 * i] = fmaxf(acc[i], 0.f);
    __syncthreads();

    float pc[CC] = {0.f, 0.f, 0.f, 0.f, 0.f};
    for (int k = tid; k < MM; k += 256) {
        float hv = sh1[k];
        #pragma unroll
        for (int c = 0; c < CC; ++c) pc[c] += W1[(size_t)c * MM + k] * hv;
    }
    const int lane = tid & 63, wid = tid >> 6;
    #pragma unroll
    for (int c = 0; c < CC; ++c) {
        float v = pc[c];
        #pragma unroll
        for (int off = 32; off > 0; off >>= 1) v += __shfl_down(v, off, 64);
        if (lane == 0) sred[c][wid] = v;
    }
    __syncthreads();
    if (tid < CC) {
        float s = sred[tid][0] + sred[tid][1] + sred[tid][2] + sred[tid][3]
                + b1[tid];
        slog[tid] = fmaxf(s, 0.f);
    }
    __syncthreads();
    if (tid < CC) {
        float mx = slog[0];
        #pragma unroll
        for (int c = 1; c < CC; ++c) mx = fmaxf(mx, slog[c]);
        float se = 0.f;
        #pragma unroll
        for (int c = 0; c < CC; ++c) se += __expf(slog[c] - mx);
        out[(size_t)b * CC + tid] = slog[tid] - mx - __logf(se);
    }
}

// ---------------------------------------------------------------------------
extern "C" void kernel_launch(void* const* d_in, const int* in_sizes, int n_in,
                              void* d_out, int out_size, void* d_ws, size_t ws_size,
                              hipStream_t stream) {
    const int*   x       = (const int*)d_in[0];
    const int*   lengths = (const int*)d_in[1];
    const float* emb     = (const float*)d_in[2];
    const float* W_ih    = (const float*)d_in[3];
    const float* W_hh    = (const float*)d_in[4];
    const float* b_ih    = (const float*)d_in[5];
    const float* b_hh    = (const float*)d_in[6];
    const float* W0      = (const float*)d_in[7];
    const float* b0      = (const float*)d_in[8];
    const float* W1      = (const float*)d_in[9];
    const float* b1      = (const float*)d_in[10];
    float* out = (float*)d_out;

    _Float16* u  = (_Float16*)d_ws;
    float*    hn = (float*)((char*)d_ws + (size_t)BB * TT * HH * sizeof(_Float16));

    dim3 g1(TT / 64, BB);
    k_embed<<<g1, 256, 0, stream>>>(x, lengths, emb, W_ih, b_ih, b_hh, u);
    k_rnn  <<<BB, 256, 0, stream>>>(lengths, W_hh, u, hn);
    k_head <<<BB, 256, 0, stream>>>(hn, W0, b0, W1, b1, out);
}

// Round 7
// 446.516 us; speedup vs baseline: 1.3992x; 1.0293x over previous
//
#include <hip/hip_runtime.h>
#include <hip/hip_bf16.h>

#define BB 128
#define TT 512
#define EE 128
#define HH 256
#define MM 1024
#define CC 5

typedef _Float16 h2 __attribute__((ext_vector_type(2)));
typedef __fp16 f16x2 __attribute__((ext_vector_type(2)));
typedef __fp16 f16x8 __attribute__((ext_vector_type(8)));
typedef float  f32x4 __attribute__((ext_vector_type(4)));

__device__ inline h2 mkh2(float a, float b) {
    return __builtin_bit_cast(h2, __builtin_amdgcn_cvt_pkrtz(a, b));
}

// pack 8 f32 -> 8 f16 (one MFMA operand fragment)
__device__ inline f16x8 pack8(float4 lo, float4 hi) {
    union { f16x2 h[4]; f16x8 v; } u;
    u.h[0] = __builtin_amdgcn_cvt_pkrtz(lo.x, lo.y);
    u.h[1] = __builtin_amdgcn_cvt_pkrtz(lo.z, lo.w);
    u.h[2] = __builtin_amdgcn_cvt_pkrtz(hi.x, hi.y);
    u.h[3] = __builtin_amdgcn_cvt_pkrtz(hi.z, hi.w);
    return u.v;
}

__device__ inline float dot2f(h2 a, h2 b, float c) {
#if __has_builtin(__builtin_amdgcn_fdot2)
    return __builtin_amdgcn_fdot2(a, b, c, false);
#else
    return c + (float)a.x * (float)b.x + (float)a.y * (float)b.y;
#endif
}

// Quad butterfly sum via DPP (VALU pipe, no LDS traffic).
__device__ inline float dpp_add4(float x) {
    int t = __builtin_amdgcn_update_dpp(0, __builtin_bit_cast(int, x), 0xB1, 0xF, 0xF, true);
    x += __builtin_bit_cast(float, t);
    t = __builtin_amdgcn_update_dpp(0, __builtin_bit_cast(int, x), 0x4E, 0xF, 0xF, true);
    x += __builtin_bit_cast(float, t);
    return x;
}

__device__ inline float fast_tanh(float x) {
    float e = __expf(2.0f * x);
    return 1.0f - 2.0f / (e + 1.0f);
}

// ---------------------------------------------------------------------------
// K1 (MFMA GEMM): u[tok][ch] = bias[ch] + emb[x[tok]] @ W_ih^T, f16 out.
// All B*T=65536 tokens (no length masking — cheaper than the bookkeeping).
// Tile: 32 tokens x 256 ch per WG (2048 WGs), K=128. Wave w owns 64 ch
// (4 col-tiles); W_ih held as 16 B-fragments in regs (loaded once); emb rows
// gathered -> f16 LDS -> A-fragments; bias in C-init; LDS-transpose epilogue
// for coalesced dwordx4 stores of u.
// Layouts (m89/m120-verified): A[m=lane&15][k=quad*8+j],
// B[k=quad*8+j][n=lane&15], D col=lane&15 row=quad*4+reg.
// ---------------------------------------------------------------------------
__global__ __launch_bounds__(256, 2)
void k_embed(const int* __restrict__ x,
             const float* __restrict__ emb, const float* __restrict__ W_ih,
             const float* __restrict__ b_ih, const float* __restrict__ b_hh,
             _Float16* __restrict__ u)
{
    const int tb   = blockIdx.x;        // 32-token tile
    const int tid  = threadIdx.x;
    const int wv   = tid >> 6;
    const int lane = tid & 63;
    const int l15  = lane & 15;
    const int quad = lane >> 4;

    __shared__ __align__(16) char lds[32 * 512];  // 16KB: A-stage(8KB)/out(16KB)

    // B fragments: B[k][n] = W_ih[n][k]; n = 64*wv + 16*ct + l15
    f16x8 bf[4][4];
    float bias[4];
    #pragma unroll
    for (int ct = 0; ct < 4; ++ct) {
        const int n = 64 * wv + 16 * ct + l15;
        const float* wp = W_ih + (size_t)n * EE;
        #pragma unroll
        for (int kc = 0; kc < 4; ++kc) {
            const float4* p = (const float4*)(wp + 32 * kc + 8 * quad);
            bf[ct][kc] = pack8(p[0], p[1]);
        }
        bias[ct] = b_ih[n] + b_hh[n];
    }

    // gather 32 emb rows -> f16 LDS A[32][128]
    {
        const int r = tid >> 3;          // row 0..31
        const int s = tid & 7;           // 16-float segment
        const int tok = x[tb * 32 + r];
        const float4* ep = (const float4*)(emb + (size_t)tok * EE + 16 * s);
        float4 a = ep[0], b = ep[1], c = ep[2], d = ep[3];
        *(f16x8*)(lds + r * 256 + 32 * s)      = pack8(a, b);
        *(f16x8*)(lds + r * 256 + 32 * s + 16) = pack8(c, d);
    }
    __syncthreads();

    f32x4 acc[2][4];
    #pragma unroll
    for (int rt = 0; rt < 2; ++rt)
        #pragma unroll
        for (int ct = 0; ct < 4; ++ct)
            acc[rt][ct] = (f32x4){bias[ct], bias[ct], bias[ct], bias[ct]};

    #pragma unroll
    for (int kc = 0; kc < 4; ++kc) {
        const int ko = (32 * kc + 8 * quad) * 2;
        f16x8 a0 = *(const f16x8*)(lds + (l15)      * 256 + ko);
        f16x8 a1 = *(const f16x8*)(lds + (16 + l15) * 256 + ko);
        #pragma unroll
        for (int ct = 0; ct < 4; ++ct) {
            acc[0][ct] = __builtin_amdgcn_mfma_f32_16x16x32_f16(a0, bf[ct][kc], acc[0][ct], 0, 0, 0);
            acc[1][ct] = __builtin_amdgcn_mfma_f32_16x16x32_f16(a1, bf[ct][kc], acc[1][ct], 0, 0, 0);
        }
    }
    __syncthreads();                     // all A-fragment reads complete

    // D -> LDS [token][ch] f16 (16KB)
    #pragma unroll
    for (int rt = 0; rt < 2; ++rt) {
        #pragma unroll
        for (int ct = 0; ct < 4; ++ct) {
            const int chb = (64 * wv + 16 * ct + l15) * 2;
            #pragma unroll
            for (int rg = 0; rg < 4; ++rg) {
                const int tok = 16 * rt + 4 * quad + rg;
                *(_Float16*)(lds + tok * 512 + chb) = (_Float16)acc[rt][ct][rg];
            }
        }
    }
    __syncthreads();

    // coalesced writeout: 32 tokens x 512B = 16KB
    {
        char* dst = (char*)u + (size_t)tb * 16384 + tid * 64;
        const char* src = lds + tid * 64;
        #pragma unroll
        for (int q = 0; q < 4; ++q)
            *(float4*)(dst + 16 * q) = *(const float4*)(src + 16 * q);
    }
}

// ---------------------------------------------------------------------------
// K2: serial scan, one workgroup per batch element. Split-K(4) + DPP.
// u staged in 64-step chunks (32 KB LDS, coalesced); inner loop LDS-only so
// __syncthreads() has no vmcnt drain. (unchanged from R6)
// ---------------------------------------------------------------------------
__global__ __launch_bounds__(256, 1)
void k_rnn(const int* __restrict__ lengths, const float* __restrict__ W_hh,
           const _Float16* __restrict__ u, float* __restrict__ hn)
{
    const int b = blockIdx.x;
    const int tid = threadIdx.x;
    const int kc = tid & 3;
    const int g  = tid >> 2;
    const int len = lengths[b];

    h2 w[4][32];
    #pragma unroll
    for (int m = 0; m < 4; ++m) {
        const float4* wr = (const float4*)(W_hh + (size_t)(4*g + m) * HH + kc*64);
        #pragma unroll
        for (int q = 0; q < 16; ++q) {
            float4 v = wr[q];
            w[m][2*q]   = mkh2(v.x, v.y);
            w[m][2*q+1] = mkh2(v.z, v.w);
        }
    }

    __shared__ char hbuf[2][512];                 // 2 x 256 f16
    __shared__ __align__(16) char ubuf[64 * 512]; // 64 steps x 256ch x 2B
    ((float*)hbuf)[tid] = 0.f;

    const int wr_off = (tid >> 6) * 128
                     + (((((tid >> 3) & 7) + 2 * (tid >> 6)) & 7) << 4)
                     + ((tid & 7) << 1);
    int roff[8];
    #pragma unroll
    for (int i = 0; i < 8; ++i)
        roff[i] = kc * 128 + (((i + 2 * kc) & 7) << 4);

    __syncthreads();

    float hlast = 0.f;
    if (len > 0) {
        const char* ubase = (const char*)(u + ((size_t)b * TT + (TT - len)) * HH);
        const int totbytes = len * 512;
        int p = 0;
        for (int c = 0; c * 64 < len; ++c) {
            const int cbase = c * 32768;
            float4 stash[8];
            #pragma unroll
            for (int q = 0; q < 8; ++q) {
                int off = cbase + q * 4096 + tid * 16;
                off = (off > totbytes - 16) ? (totbytes - 16) : off;
                stash[q] = *(const float4*)(ubase + off);
            }
            #pragma unroll
            for (int q = 0; q < 8; ++q)
                *(float4*)(ubuf + q * 4096 + tid * 16) = stash[q];
            __syncthreads();
            const int steps = (len - c * 64 < 64) ? (len - c * 64) : 64;
            for (int s = 0; s < steps; ++s) {
                const _Float16 uv = *(const _Float16*)(ubuf + s * 512 + tid * 2);
                const char* hb = hbuf[p];
                float a0 = 0.f, a1 = 0.f, a2 = 0.f, a3 = 0.f;
                #pragma unroll
                for (int i = 0; i < 8; ++i) {
                    float4 hv = *(const float4*)(hb + roff[i]);
                    h2* hp = (h2*)&hv;
                    #pragma unroll
                    for (int z = 0; z < 4; ++z) {
                        a0 = dot2f(w[0][4*i+z], hp[z], a0);
                        a1 = dot2f(w[1][4*i+z], hp[z], a1);
                        a2 = dot2f(w[2][4*i+z], hp[z], a2);
                        a3 = dot2f(w[3][4*i+z], hp[z], a3);
                    }
                }
                a0 = dpp_add4(a0); a1 = dpp_add4(a1);
                a2 = dpp_add4(a2); a3 = dpp_add4(a3);
                float v = (kc == 0) ? a0 : (kc == 1) ? a1
                        : (kc == 2) ? a2 : a3;
                const float hnew = fast_tanh(v + (float)uv);
                hlast = hnew;
                *(_Float16*)(hbuf[p ^ 1] + wr_off) = (_Float16)hnew;
                __syncthreads();
                p ^= 1;
            }
        }
    }
    hn[(size_t)b * HH + tid] = hlast;
}

// ---------------------------------------------------------------------------
// K3: MLP head + log_softmax. One block per batch row. (unchanged)
// ---------------------------------------------------------------------------
__global__ __launch_bounds__(256, 2)
void k_head(const float* __restrict__ hn, const float* __restrict__ W0,
            const float* __restrict__ b0, const float* __restrict__ W1,
            const float* __restrict__ b1, float* __restrict__ out)
{
    const int b = blockIdx.x;
    const int tid = threadIdx.x;
    __shared__ float sh[HH];
    __shared__ float sh1[MM];
    __shared__ float sred[CC][4];
    __shared__ float slog[CC];

    sh[tid] = hn[(size_t)b * HH + tid];
    __syncthreads();

    float acc[4];
    #pragma unroll
    for (int i = 0; i < 4; ++i) acc[i] = b0[tid + 256 * i];
    const float4* sh4 = (const float4*)sh;
    for (int k4 = 0; k4 < HH / 4; ++k4) {
        float4 hv = sh4[k4];
        #pragma unroll
        for (int i = 0; i < 4; ++i) {
            float4 wv = ((const float4*)(W0 + (size_t)(tid + 256 * i) * HH))[k4];
            acc[i] += wv.x * hv.x + wv.y * hv.y + wv.z * hv.z + wv.w * hv.w;
        }
    }
    #pragma unroll
    for (int i = 0; i < 4; ++i) sh1[tid + 256 * i] = fmaxf(acc[i], 0.f);
    __syncthreads();

    float pc[CC] = {0.f, 0.f, 0.f, 0.f, 0.f};
    for (int k = tid; k < MM; k += 256) {
        float hv = sh1[k];
        #pragma unroll
        for (int c = 0; c < CC; ++c) pc[c] += W1[(size_t)c * MM + k] * hv;
    }
    const int lane = tid & 63, wid = tid >> 6;
    #pragma unroll
    for (int c = 0; c < CC; ++c) {
        float v = pc[c];
        #pragma unroll
        for (int off = 32; off > 0; off >>= 1) v += __shfl_down(v, off, 64);
        if (lane == 0) sred[c][wid] = v;
    }
    __syncthreads();
    if (tid < CC) {
        float s = sred[tid][0] + sred[tid][1] + sred[tid][2] + sred[tid][3]
                + b1[tid];
        slog[tid] = fmaxf(s, 0.f);
    }
    __syncthreads();
    if (tid < CC) {
        float mx = slog[0];
        #pragma unroll
        for (int c = 1; c < CC; ++c) mx = fmaxf(mx, slog[c]);
        float se = 0.f;
        #pragma unroll
        for (int c = 0; c < CC; ++c) se += __expf(slog[c] - mx);
        out[(size_t)b * CC + tid] = slog[tid] - mx - __logf(se);
    }
}

// ---------------------------------------------------------------------------
extern "C" void kernel_launch(void* const* d_in, const int* in_sizes, int n_in,
                              void* d_out, int out_size, void* d_ws, size_t ws_size,
                              hipStream_t stream) {
    const int*   x       = (const int*)d_in[0];
    const int*   lengths = (const int*)d_in[1];
    const float* emb     = (const float*)d_in[2];
    const float* W_ih    = (const float*)d_in[3];
    const float* W_hh    = (const float*)d_in[4];
    const float* b_ih    = (const float*)d_in[5];
    const float* b_hh    = (const float*)d_in[6];
    const float* W0      = (const float*)d_in[7];
    const float* b0      = (const float*)d_in[8];
    const float* W1      = (const float*)d_in[9];
    const float* b1      = (const float*)d_in[10];
    float* out = (float*)d_out;

    _Float16* u  = (_Float16*)d_ws;
    float*    hn = (float*)((char*)d_ws + (size_t)BB * TT * HH * sizeof(_Float16));

    k_embed<<<(BB * TT) / 32, 256, 0, stream>>>(x, emb, W_ih, b_ih, b_hh, u);
    k_rnn  <<<BB, 256, 0, stream>>>(lengths, W_hh, u, hn);
    k_head <<<BB, 256, 0, stream>>>(hn, W0, b0, W1, b1, out);
}